// Round 2
// baseline (1258.543 us; speedup 1.0000x reference)
//
#include <hip/hip_runtime.h>
#include <math.h>

typedef _Float16 f16;
typedef f16 f16x8 __attribute__((ext_vector_type(8)));
typedef f16 f16x4 __attribute__((ext_vector_type(4)));
typedef float f32x4 __attribute__((ext_vector_type(4)));

// d_out layout (float offsets): out | weights | pos_bias
#define W_OFF   (2*2048*1024)               // 4,194,304
#define PB_OFF  (W_OFF + 2LL*16*2048*2048)  // 138,412,032

#define NEG_BIG (-1.0e30f)

// async global -> LDS, 16B per lane. LDS dest = wave-uniform base + lane*16.
__device__ __forceinline__ void gload_lds16(const f16* g, f16* l) {
    __builtin_amdgcn_global_load_lds(
        (const __attribute__((address_space(1))) void*)g,
        (__attribute__((address_space(3))) void*)l,
        16, 0, 0);
}

// T5 relative-position bucket, fp32 math ordered like the numpy reference.
__device__ __forceinline__ int rel_bucket(int rel) {
    int ret = rel > 0 ? 32 : 0;
    int n = rel < 0 ? -rel : rel;
    if (n < 16) return ret + n;
    float fn = (float)n;
    float t = logf(fn * (1.0f / 16.0f));
    t = t / 1.1394343f;                    // fp32(np.log(50/16))
    int large = 16 + (int)(t * 16.0f);
    if (large > 31) large = 31;
    return ret + large;
}

// ---------- small prep kernels ----------

__global__ __launch_bounds__(256)
void conv_f16_kernel(const float* __restrict__ in, f16* __restrict__ out) {
    size_t i = ((size_t)blockIdx.x * 256 + threadIdx.x) * 4;
    float4 v = *(const float4*)&in[i];
    f16x4 h = { (f16)v.x, (f16)v.y, (f16)v.z, (f16)v.w };
    *(f16x4*)&out[i] = h;
}

// W (1024x1024 fp32, [k][n]) -> Wt (fp16, [n][k])
__global__ __launch_bounds__(256)
void transpose_w_kernel(const float* __restrict__ W, f16* __restrict__ Wt) {
    __shared__ float tile[64 * 68];
    const int tid = threadIdx.x;
    const int bi = blockIdx.x, bj = blockIdx.y;  // bi: k-tile, bj: n-tile
    #pragma unroll
    for (int it = 0; it < 4; ++it) {
        int slot = tid + it * 256;               // 0..1023
        int row = slot >> 4, col4 = (slot & 15) * 4;
        float4 v = *(const float4*)&W[(size_t)(bi * 64 + row) * 1024 + bj * 64 + col4];
        *(float4*)&tile[row * 68 + col4] = v;
    }
    __syncthreads();
    #pragma unroll
    for (int it = 0; it < 4; ++it) {
        int slot = tid + it * 256;
        int nrow = slot >> 4, kcol4 = (slot & 15) * 4;
        f16x4 h;
        #pragma unroll
        for (int j = 0; j < 4; ++j)
            h[j] = (f16)tile[(kcol4 + j) * 68 + nrow];
        *(f16x4*)&Wt[(size_t)(bj * 64 + nrow) * 1024 + bi * 64 + kcol4] = h;
    }
}

// bias_delta table: tbl[h*4096 + dd] = rel_table[bucket(dd-2047)][h]
__global__ __launch_bounds__(256)
void bias_tbl_kernel(const float* __restrict__ rel_table, float* __restrict__ tbl) {
    int idx = blockIdx.x * 256 + threadIdx.x;   // 0..65535
    int h = idx >> 12, dd = idx & 4095;
    tbl[idx] = rel_table[rel_bucket(dd - 2047) * 16 + h];
}

// concat bq|bk|bv -> bqkv[3072]
__global__ __launch_bounds__(256)
void concat_bias_kernel(const float* __restrict__ bq, const float* __restrict__ bk,
                        const float* __restrict__ bv, float* __restrict__ o) {
    int i = blockIdx.x * 256 + threadIdx.x;     // 0..3071
    float v = i < 1024 ? bq[i] : (i < 2048 ? bk[i - 1024] : bv[i - 2048]);
    o[i] = v;
}

// v (bh, s, d) fp16 -> vt (bh, d, s) fp16
__global__ __launch_bounds__(256)
void transpose_v_kernel(const f16* __restrict__ vh, f16* __restrict__ vt) {
    __shared__ f16 tile[64 * 72];
    const int tid = threadIdx.x;
    const int st = blockIdx.x, bh = blockIdx.y;
    #pragma unroll
    for (int it = 0; it < 2; ++it) {
        int slot = tid + it * 256;               // 0..511
        int row = slot >> 3, col8 = (slot & 7) * 8;
        f16x8 v = *(const f16x8*)&vh[((size_t)bh * 2048 + st * 64 + row) * 64 + col8];
        *(f16x8*)&tile[row * 72 + col8] = v;
    }
    __syncthreads();
    #pragma unroll
    for (int it = 0; it < 2; ++it) {
        int slot = tid + it * 256;
        int drow = slot >> 3, scol8 = (slot & 7) * 8;
        f16x8 r;
        #pragma unroll
        for (int j = 0; j < 8; ++j)
            r[j] = tile[(scol8 + j) * 72 + drow];
        *(f16x8*)&vt[((size_t)bh * 64 + drow) * 2048 + st * 64 + scol8] = r;
    }
}

// ---------- fp16 MFMA GEMM: C[4096 x N] = A[4096x1024] * Bt^T + bias ----------
// A row-major fp16, Bt = B^T row-major fp16 (N x K). Staging via global_load_lds.
// mode 0: fp32 row-major out (N=1024).  mode 1: fp16 (buf,b,h,s,d) out (N=3072, qkv fused).
__global__ __launch_bounds__(256)
void gemm_f16(const f16* __restrict__ A, const f16* __restrict__ Bt,
              const float* __restrict__ bias, void* __restrict__ Cout, int mode)
{
    __shared__ f16 aLDS[128 * 32];   // frag-linear: [mt(8)][lane(64)][8]
    __shared__ f16 bLDS[128 * 32];
    const int tid = threadIdx.x;
    const int lane = tid & 63, wv = tid >> 6;
    const int quad = lane >> 4, l15 = lane & 15;
    const int wm = (wv & 1) * 64, wn = (wv >> 1) * 64;
    const int bm = blockIdx.y * 128, bn = blockIdx.x * 128;

    f32x4 acc[4][4];
    #pragma unroll
    for (int i = 0; i < 4; ++i)
        #pragma unroll
        for (int j = 0; j < 4; ++j)
            acc[i][j] = (f32x4){0.f, 0.f, 0.f, 0.f};

    for (int k0 = 0; k0 < 1024; k0 += 32) {
        __syncthreads();                         // prior iter's ds_reads done
        #pragma unroll
        for (int s = 0; s < 2; ++s) {
            int row = (wv + s * 4) * 16 + l15;   // mt = wv + s*4 (wave-uniform)
            gload_lds16(&A [(size_t)(bm + row) * 1024 + k0 + quad * 8],
                        &aLDS[(size_t)(s * 256 + wv * 64) * 8]);
            gload_lds16(&Bt[(size_t)(bn + row) * 1024 + k0 + quad * 8],
                        &bLDS[(size_t)(s * 256 + wv * 64) * 8]);
        }
        __syncthreads();                         // drains vmcnt(0): LDS ready
        f16x8 af[4], bf[4];
        #pragma unroll
        for (int i = 0; i < 4; ++i) {
            af[i] = *(const f16x8*)&aLDS[(((wm >> 4) + i) * 64 + lane) * 8];
            bf[i] = *(const f16x8*)&bLDS[(((wn >> 4) + i) * 64 + lane) * 8];
        }
        #pragma unroll
        for (int i = 0; i < 4; ++i)
            #pragma unroll
            for (int j = 0; j < 4; ++j)
                acc[i][j] = __builtin_amdgcn_mfma_f32_16x16x32_f16(af[i], bf[j], acc[i][j], 0, 0, 0);
    }

    #pragma unroll
    for (int j = 0; j < 4; ++j) {
        int n = bn + wn + j * 16 + l15;
        float bz = bias[n];
        #pragma unroll
        for (int i = 0; i < 4; ++i) {
            #pragma unroll
            for (int r = 0; r < 4; ++r) {
                int m = bm + wm + i * 16 + quad * 4 + r;
                float val = acc[i][j][r] + bz;
                if (mode == 0) {
                    ((float*)Cout)[(size_t)m * 1024 + n] = val;
                } else {
                    int b = m >> 11, srow = m & 2047;
                    int buf = n >> 10, h = (n >> 6) & 15, d = n & 63;
                    ((f16*)Cout)[(size_t)buf * 4194304 +
                                 (((size_t)(b * 16 + h) * 2048 + srow) << 6) + d] = (f16)val;
                }
            }
        }
    }
}

// ---------- attention ----------
// Per block: one (bh, 64-query tile). Wave w owns q rows [qt0+16w, qt0+16w+16).
// K/V fragments loaded DIRECTLY from global (L1/L2-resident: 256KB each per bh)
// -- no LDS staging, no barriers in the main loops (learn_hip m169 pattern).
// XCD swizzle: each XCD owns 4 whole bh -> K/V working set 2MB < 4MB L2.
__global__ __launch_bounds__(256)
void attn_f16(const f16* __restrict__ qh, const f16* __restrict__ kh,
              const f16* __restrict__ vth, const float* __restrict__ tbl,
              const int* __restrict__ mask, float* __restrict__ wout,
              f16* __restrict__ ctxh)
{
    __shared__ float biasL[4096];        // 16 KB
    __shared__ float maskL[2048];        // 8 KB (holds mask - 20 fold)
    __shared__ f16 wnat[4 * 16 * 88];    // 11 KB [wave][q16][key64, stride 88]

    const int tid = threadIdx.x, lane = tid & 63, wv = tid >> 6;
    const int quad = lane >> 4, l15 = lane & 15;

    // bijective XCD swizzle: lin -> (lin&7)*128 + lin>>3 ; bh = nl>>5
    const int lin = blockIdx.y * 32 + blockIdx.x;
    const int nl = (lin & 7) * 128 + (lin >> 3);
    const int bh = nl >> 5, b = bh >> 4, h = bh & 15;
    const int qt0 = (nl & 31) * 64;

    for (int i = tid; i < 1024; i += 256)
        *(float4*)&biasL[i * 4] = *(const float4*)&tbl[h * 4096 + i * 4];
    for (int i = tid; i < 512; i += 256) {
        int4 mv = *(const int4*)&mask[b * 2048 + i * 4];
        float4 f;
        f.x = mv.x ? NEG_BIG : -20.f;  f.y = mv.y ? NEG_BIG : -20.f;
        f.z = mv.z ? NEG_BIG : -20.f;  f.w = mv.w ? NEG_BIG : -20.f;
        *(float4*)&maskL[i * 4] = f;
    }

    const int q0 = qt0 + wv * 16;
    f16x8 aq[2];
    #pragma unroll
    for (int ds = 0; ds < 2; ++ds)
        aq[ds] = *(const f16x8*)&qh[((size_t)bh * 2048 + q0 + l15) * 64 + ds * 32 + quad * 8];
    __syncthreads();   // biasL/maskL visible; the ONLY block-wide barrier

    const int qrow_base = q0 + quad * 4;
    const f16* kB = kh  + (size_t)bh * 2048 * 64 + quad * 8;   // [s][d], quad*8 folded
    const f16* vB = vth + (size_t)bh * 64 * 2048 + quad * 8;   // [d][s], quad*8 folded

    float lI[4] = {0.f, 0.f, 0.f, 0.f};

    // ---- pass A: l[r] = sum_k exp(s + bias + (mask-20)) ----
    for (int c = 0; c < 32; ++c) {
        f16x8 bf[2][4];
        #pragma unroll
        for (int nt = 0; nt < 4; ++nt) {
            const f16* kp = kB + (size_t)(c * 64 + nt * 16 + l15) * 64;
            bf[0][nt] = *(const f16x8*)&kp[0];
            bf[1][nt] = *(const f16x8*)&kp[32];
        }
        #pragma unroll
        for (int nt = 0; nt < 4; ++nt) {
            f32x4 s4 = (f32x4){0.f, 0.f, 0.f, 0.f};
            s4 = __builtin_amdgcn_mfma_f32_16x16x32_f16(aq[0], bf[0][nt], s4, 0, 0, 0);
            s4 = __builtin_amdgcn_mfma_f32_16x16x32_f16(aq[1], bf[1][nt], s4, 0, 0, 0);
            int k = c * 64 + nt * 16 + l15;
            float mk = maskL[k];
            int bi = k - qrow_base + 2047;
            #pragma unroll
            for (int r = 0; r < 4; ++r)
                lI[r] += __expf(s4[r] + biasL[bi - r] + mk);
        }
    }
    #pragma unroll
    for (int r = 0; r < 4; ++r) {
        float l = lI[r];
        l += __shfl_xor(l, 1, 64);
        l += __shfl_xor(l, 2, 64);
        l += __shfl_xor(l, 4, 64);
        l += __shfl_xor(l, 8, 64);
        lI[r] = 1.0f / l;
    }

    // ---- pass B: recompute scores, write weights, accumulate O = W*V ----
    float* wbase = wout + (size_t)bh * 2048 * 2048;
    f32x4 oacc[4];
    #pragma unroll
    for (int nt = 0; nt < 4; ++nt) oacc[nt] = (f32x4){0.f, 0.f, 0.f, 0.f};

    for (int c = 0; c < 32; ++c) {
        f16x8 bf[2][4];
        #pragma unroll
        for (int nt = 0; nt < 4; ++nt) {
            const f16* kp = kB + (size_t)(c * 64 + nt * 16 + l15) * 64;
            bf[0][nt] = *(const f16x8*)&kp[0];
            bf[1][nt] = *(const f16x8*)&kp[32];
        }
        f16x8 vf[2][4];   // issued early: consumed only in PV, latency hides under QK+exp
        #pragma unroll
        for (int nt = 0; nt < 4; ++nt) {
            const f16* vp = vB + (size_t)(nt * 16 + l15) * 2048 + c * 64;
            vf[0][nt] = *(const f16x8*)&vp[0];
            vf[1][nt] = *(const f16x8*)&vp[32];
        }

        #pragma unroll
        for (int nt = 0; nt < 4; ++nt) {
            f32x4 s4 = (f32x4){0.f, 0.f, 0.f, 0.f};
            s4 = __builtin_amdgcn_mfma_f32_16x16x32_f16(aq[0], bf[0][nt], s4, 0, 0, 0);
            s4 = __builtin_amdgcn_mfma_f32_16x16x32_f16(aq[1], bf[1][nt], s4, 0, 0, 0);
            int k = c * 64 + nt * 16 + l15;
            float mk = maskL[k];
            int bi = k - qrow_base + 2047;
            float* wp = wbase + (size_t)qrow_base * 2048 + k;
            #pragma unroll
            for (int r = 0; r < 4; ++r) {
                float w = __expf(s4[r] + biasL[bi - r] + mk) * lI[r];
                wp[(size_t)r * 2048] = w;
                wnat[wv * 1408 + (quad * 4 + r) * 88 + nt * 16 + l15] = (f16)w;
            }
        }
        // per-wave LDS RAW on wnat: compiler-inserted lgkmcnt; no barrier needed
        #pragma unroll
        for (int ks = 0; ks < 2; ++ks) {
            f16x8 wf = *(const f16x8*)&wnat[wv * 1408 + l15 * 88 + ks * 32 + quad * 8];
            #pragma unroll
            for (int nt = 0; nt < 4; ++nt)
                oacc[nt] = __builtin_amdgcn_mfma_f32_16x16x32_f16(wf, vf[ks][nt], oacc[nt], 0, 0, 0);
        }
    }

    #pragma unroll
    for (int nt = 0; nt < 4; ++nt) {
        int d = nt * 16 + l15;
        #pragma unroll
        for (int r = 0; r < 4; ++r) {
            int q = qrow_base + r;
            ctxh[((size_t)(b * 2048) + q) * 1024 + h * 64 + d] = (f16)oacc[nt][r];
        }
    }
}

// ---------- pos_bias (identical math to round 1; runs last over scratch) ----------
__global__ __launch_bounds__(256)
void posbias_kernel(const float* __restrict__ rel_table, float* __restrict__ pb)
{
    size_t g = ((size_t)blockIdx.x * 256 + threadIdx.x) * 4;
    int k = (int)(g & 2047);
    int q = (int)((g >> 11) & 2047);
    int h = (int)(g >> 22);
    float4 r;
    float* rp = (float*)&r;
    #pragma unroll
    for (int j = 0; j < 4; ++j)
        rp[j] = rel_table[rel_bucket(k + j - q) * 16 + h];
    *(float4*)&pb[g] = r;
}

extern "C" void kernel_launch(void* const* d_in, const int* in_sizes, int n_in,
                              void* d_out, int out_size, void* d_ws, size_t ws_size,
                              hipStream_t stream) {
    const float* x    = (const float*)d_in[0];
    const float* Wq   = (const float*)d_in[1];
    const float* bq   = (const float*)d_in[2];
    const float* Wk   = (const float*)d_in[3];
    const float* bk   = (const float*)d_in[4];
    const float* Wv   = (const float*)d_in[5];
    const float* bv   = (const float*)d_in[6];
    const float* Wo   = (const float*)d_in[7];
    const float* bo   = (const float*)d_in[8];
    const float* rt   = (const float*)d_in[9];
    const int*   mask = (const int*)d_in[10];

    float* out = (float*)d_out;
    float* wts = out + W_OFF;
    float* pb  = out + PB_OFF;

    // Scratch in the pos_bias region (67.1M floats); pos_bias written LAST.
    float* tbl  = pb;                         // 65,536 floats
    f16*   xh   = (f16*)(pb + 65536);         // 4,194,304 halfs
    f16*   wqt  = (f16*)(pb + 2162688);       // wq|wk|wv contiguous = [3072][1024]
    f16*   wkt  = (f16*)(pb + 2686976);
    f16*   wvt  = (f16*)(pb + 3211264);
    f16*   wot  = (f16*)(pb + 3735552);
    f16*   qh   = (f16*)(pb + 4259840);       // q|k|v contiguous, 4,194,304 halfs each
    f16*   kh   = (f16*)(pb + 6356992);
    f16*   vh   = (f16*)(pb + 8454144);
    f16*   vth  = (f16*)(pb + 10551296);
    f16*   ctxh = (f16*)(pb + 12648448);
    float* bqkv = pb + 14745600;              // 3072 floats

    dim3 blk(256);
    conv_f16_kernel<<<dim3(4096), blk, 0, stream>>>(x, xh);
    transpose_w_kernel<<<dim3(16, 16), blk, 0, stream>>>(Wq, wqt);
    transpose_w_kernel<<<dim3(16, 16), blk, 0, stream>>>(Wk, wkt);
    transpose_w_kernel<<<dim3(16, 16), blk, 0, stream>>>(Wv, wvt);
    transpose_w_kernel<<<dim3(16, 16), blk, 0, stream>>>(Wo, wot);
    bias_tbl_kernel<<<dim3(256), blk, 0, stream>>>(rt, tbl);
    concat_bias_kernel<<<dim3(12), blk, 0, stream>>>(bq, bk, bv, bqkv);

    // fused QKV projection: C[4096x3072], 768 blocks = 3/CU
    gemm_f16<<<dim3(24, 32), blk, 0, stream>>>(xh, wqt, bqkv, qh, 1);
    transpose_v_kernel<<<dim3(32, 32), blk, 0, stream>>>(vh, vth);

    attn_f16<<<dim3(32, 32), blk, 0, stream>>>(qh, kh, vth, tbl, mask, wts, ctxh);

    gemm_f16<<<dim3(8, 32), blk, 0, stream>>>(ctxh, wot, bo, out, 0);
    posbias_kernel<<<dim3(65536), blk, 0, stream>>>(rt, pb);
}

// Round 3
// 1114.609 us; speedup vs baseline: 1.1291x; 1.1291x over previous
//
#include <hip/hip_runtime.h>
#include <math.h>

typedef _Float16 f16;
typedef f16 f16x8 __attribute__((ext_vector_type(8)));
typedef f16 f16x4 __attribute__((ext_vector_type(4)));
typedef float f32x4 __attribute__((ext_vector_type(4)));

// d_out layout (float offsets): out | weights | pos_bias
#define W_OFF   (2*2048*1024)               // 4,194,304
#define PB_OFF  (W_OFF + 2LL*16*2048*2048)  // 138,412,032

#define NEG_BIG (-1.0e30f)

// async global -> LDS, 16B per lane. LDS dest = wave-uniform base + lane*16.
__device__ __forceinline__ void gload_lds16(const f16* g, f16* l) {
    __builtin_amdgcn_global_load_lds(
        (const __attribute__((address_space(1))) void*)g,
        (__attribute__((address_space(3))) void*)l,
        16, 0, 0);
}

// T5 relative-position bucket, fp32 math ordered like the numpy reference.
__device__ __forceinline__ int rel_bucket(int rel) {
    int ret = rel > 0 ? 32 : 0;
    int n = rel < 0 ? -rel : rel;
    if (n < 16) return ret + n;
    float fn = (float)n;
    float t = logf(fn * (1.0f / 16.0f));
    t = t / 1.1394343f;                    // fp32(np.log(50/16))
    int large = 16 + (int)(t * 16.0f);
    if (large > 31) large = 31;
    return ret + large;
}

// ---------- small prep kernels ----------

__global__ __launch_bounds__(256)
void conv_f16_kernel(const float* __restrict__ in, f16* __restrict__ out) {
    size_t i = ((size_t)blockIdx.x * 256 + threadIdx.x) * 4;
    float4 v = *(const float4*)&in[i];
    f16x4 h = { (f16)v.x, (f16)v.y, (f16)v.z, (f16)v.w };
    *(f16x4*)&out[i] = h;
}

// W (1024x1024 fp32, [k][n]) -> Wt (fp16, [n][k])
__global__ __launch_bounds__(256)
void transpose_w_kernel(const float* __restrict__ W, f16* __restrict__ Wt) {
    __shared__ float tile[64 * 68];
    const int tid = threadIdx.x;
    const int bi = blockIdx.x, bj = blockIdx.y;  // bi: k-tile, bj: n-tile
    #pragma unroll
    for (int it = 0; it < 4; ++it) {
        int slot = tid + it * 256;               // 0..1023
        int row = slot >> 4, col4 = (slot & 15) * 4;
        float4 v = *(const float4*)&W[(size_t)(bi * 64 + row) * 1024 + bj * 64 + col4];
        *(float4*)&tile[row * 68 + col4] = v;
    }
    __syncthreads();
    #pragma unroll
    for (int it = 0; it < 4; ++it) {
        int slot = tid + it * 256;
        int nrow = slot >> 4, kcol4 = (slot & 15) * 4;
        f16x4 h;
        #pragma unroll
        for (int j = 0; j < 4; ++j)
            h[j] = (f16)tile[(kcol4 + j) * 68 + nrow];
        *(f16x4*)&Wt[(size_t)(bj * 64 + nrow) * 1024 + bi * 64 + kcol4] = h;
    }
}

// bias_delta table: tbl[h*4096 + dd] = rel_table[bucket(dd-2047)][h]
__global__ __launch_bounds__(256)
void bias_tbl_kernel(const float* __restrict__ rel_table, float* __restrict__ tbl) {
    int idx = blockIdx.x * 256 + threadIdx.x;   // 0..65535
    int h = idx >> 12, dd = idx & 4095;
    tbl[idx] = rel_table[rel_bucket(dd - 2047) * 16 + h];
}

// concat bq|bk|bv -> bqkv[3072]
__global__ __launch_bounds__(256)
void concat_bias_kernel(const float* __restrict__ bq, const float* __restrict__ bk,
                        const float* __restrict__ bv, float* __restrict__ o) {
    int i = blockIdx.x * 256 + threadIdx.x;     // 0..3071
    float v = i < 1024 ? bq[i] : (i < 2048 ? bk[i - 1024] : bv[i - 2048]);
    o[i] = v;
}

// v (bh, s, d) fp16 -> vt (bh, d, s) fp16
__global__ __launch_bounds__(256)
void transpose_v_kernel(const f16* __restrict__ vh, f16* __restrict__ vt) {
    __shared__ f16 tile[64 * 72];
    const int tid = threadIdx.x;
    const int st = blockIdx.x, bh = blockIdx.y;
    #pragma unroll
    for (int it = 0; it < 2; ++it) {
        int slot = tid + it * 256;               // 0..511
        int row = slot >> 3, col8 = (slot & 7) * 8;
        f16x8 v = *(const f16x8*)&vh[((size_t)bh * 2048 + st * 64 + row) * 64 + col8];
        *(f16x8*)&tile[row * 72 + col8] = v;
    }
    __syncthreads();
    #pragma unroll
    for (int it = 0; it < 2; ++it) {
        int slot = tid + it * 256;
        int drow = slot >> 3, scol8 = (slot & 7) * 8;
        f16x8 r;
        #pragma unroll
        for (int j = 0; j < 8; ++j)
            r[j] = tile[(scol8 + j) * 72 + drow];
        *(f16x8*)&vt[((size_t)bh * 64 + drow) * 2048 + st * 64 + scol8] = r;
    }
}

// ---------- fp16 MFMA GEMM: C[4096 x N] = A[4096x1024] * Bt^T + bias ----------
// A row-major fp16, Bt = B^T row-major fp16 (N x K). Staging via global_load_lds.
// mode 0: fp32 row-major out (N=1024).  mode 1: fp16 (buf,b,h,s,d) out (N=3072, qkv fused).
__global__ __launch_bounds__(256)
void gemm_f16(const f16* __restrict__ A, const f16* __restrict__ Bt,
              const float* __restrict__ bias, void* __restrict__ Cout, int mode)
{
    __shared__ f16 aLDS[128 * 32];   // frag-linear: [mt(8)][lane(64)][8]
    __shared__ f16 bLDS[128 * 32];
    const int tid = threadIdx.x;
    const int lane = tid & 63, wv = tid >> 6;
    const int quad = lane >> 4, l15 = lane & 15;
    const int wm = (wv & 1) * 64, wn = (wv >> 1) * 64;
    const int bm = blockIdx.y * 128, bn = blockIdx.x * 128;

    f32x4 acc[4][4];
    #pragma unroll
    for (int i = 0; i < 4; ++i)
        #pragma unroll
        for (int j = 0; j < 4; ++j)
            acc[i][j] = (f32x4){0.f, 0.f, 0.f, 0.f};

    for (int k0 = 0; k0 < 1024; k0 += 32) {
        __syncthreads();                         // prior iter's ds_reads done
        #pragma unroll
        for (int s = 0; s < 2; ++s) {
            int row = (wv + s * 4) * 16 + l15;   // mt = wv + s*4 (wave-uniform)
            gload_lds16(&A [(size_t)(bm + row) * 1024 + k0 + quad * 8],
                        &aLDS[(size_t)(s * 256 + wv * 64) * 8]);
            gload_lds16(&Bt[(size_t)(bn + row) * 1024 + k0 + quad * 8],
                        &bLDS[(size_t)(s * 256 + wv * 64) * 8]);
        }
        __syncthreads();                         // drains vmcnt(0): LDS ready
        f16x8 af[4], bf[4];
        #pragma unroll
        for (int i = 0; i < 4; ++i) {
            af[i] = *(const f16x8*)&aLDS[(((wm >> 4) + i) * 64 + lane) * 8];
            bf[i] = *(const f16x8*)&bLDS[(((wn >> 4) + i) * 64 + lane) * 8];
        }
        #pragma unroll
        for (int i = 0; i < 4; ++i)
            #pragma unroll
            for (int j = 0; j < 4; ++j)
                acc[i][j] = __builtin_amdgcn_mfma_f32_16x16x32_f16(af[i], bf[j], acc[i][j], 0, 0, 0);
    }

    #pragma unroll
    for (int j = 0; j < 4; ++j) {
        int n = bn + wn + j * 16 + l15;
        float bz = bias[n];
        #pragma unroll
        for (int i = 0; i < 4; ++i) {
            #pragma unroll
            for (int r = 0; r < 4; ++r) {
                int m = bm + wm + i * 16 + quad * 4 + r;
                float val = acc[i][j][r] + bz;
                if (mode == 0) {
                    ((float*)Cout)[(size_t)m * 1024 + n] = val;
                } else {
                    int b = m >> 11, srow = m & 2047;
                    int buf = n >> 10, h = (n >> 6) & 15, d = n & 63;
                    ((f16*)Cout)[(size_t)buf * 4194304 +
                                 (((size_t)(b * 16 + h) * 2048 + srow) << 6) + d] = (f16)val;
                }
            }
        }
    }
}

// ---------- attention ----------
// Per block: one (bh, 64-query tile). Wave w owns q rows [qt0+16w, qt0+16w+16).
// K/V staged in LDS once per block (shared by 4 waves) via async global_load_lds
// width-16 -- removes the register round-trip (m97 lever) while keeping minimal
// L1/L2 traffic. 2 barriers/iter, 51KB LDS -> 3 blocks/CU (R0-proven structure).
__global__ __launch_bounds__(256)
void attn_f16(const f16* __restrict__ qh, const f16* __restrict__ kh,
              const f16* __restrict__ vth, const float* __restrict__ tbl,
              const int* __restrict__ mask, float* __restrict__ wout,
              f16* __restrict__ ctxh)
{
    __shared__ float biasL[4096];        // 16 KB
    __shared__ float maskL[2048];        // 8 KB (holds mask - 20 fold)
    __shared__ f16 kL[8 * 64 * 8];       // 8 KB  [frag(dstep*4+nt)][lane][8]
    __shared__ f16 vL[8 * 64 * 8];       // 8 KB  [frag(ks*4+nt)][lane][8]
    __shared__ f16 wnat[4 * 16 * 88];    // 11 KB [wave][q16][key64, stride 88]

    const int tid = threadIdx.x, lane = tid & 63, wv = tid >> 6;
    const int quad = lane >> 4, l15 = lane & 15;

    // bijective XCD swizzle: each XCD ends up owning 4 whole bh (K/V 2MB < 4MB L2)
    const int lin = blockIdx.y * 32 + blockIdx.x;
    const int nl = (lin & 7) * 128 + (lin >> 3);
    const int bh = nl >> 5, b = bh >> 4, h = bh & 15;
    const int qt0 = (nl & 31) * 64;

    for (int i = tid; i < 1024; i += 256)
        *(float4*)&biasL[i * 4] = *(const float4*)&tbl[h * 4096 + i * 4];
    for (int i = tid; i < 512; i += 256) {
        int4 mv = *(const int4*)&mask[b * 2048 + i * 4];
        float4 f;
        f.x = mv.x ? NEG_BIG : -20.f;  f.y = mv.y ? NEG_BIG : -20.f;
        f.z = mv.z ? NEG_BIG : -20.f;  f.w = mv.w ? NEG_BIG : -20.f;
        *(float4*)&maskL[i * 4] = f;
    }

    const int q0 = qt0 + wv * 16;
    f16x8 aq[2];
    #pragma unroll
    for (int ds = 0; ds < 2; ++ds)
        aq[ds] = *(const f16x8*)&qh[((size_t)bh * 2048 + q0 + l15) * 64 + ds * 32 + quad * 8];

    const int qrow_base = q0 + quad * 4;
    const f16* kB = kh  + (size_t)bh * 2048 * 64;   // [s][d]
    const f16* vB = vth + (size_t)bh * 64 * 2048;   // [d][s]

    float lI[4] = {0.f, 0.f, 0.f, 0.f};

    // ---- pass A: l[r] = sum_k exp(s + bias + (mask-20)) ----
    for (int c = 0; c < 32; ++c) {
        __syncthreads();                 // iter c-1 ds_reads done (also covers biasL/maskL at c=0)
        #pragma unroll
        for (int s = 0; s < 2; ++s) {
            int f = wv + s * 4;          // frag = dstep*4 + nt (wave-uniform)
            int dstep = f >> 2, nt = f & 3;
            gload_lds16(&kB[(size_t)(c * 64 + nt * 16 + l15) * 64 + dstep * 32 + quad * 8],
                        &kL[(size_t)(s * 256 + wv * 64) * 8]);
        }
        __syncthreads();                 // drains vmcnt(0): kL ready
        #pragma unroll
        for (int nt = 0; nt < 4; ++nt) {
            f32x4 s4 = (f32x4){0.f, 0.f, 0.f, 0.f};
            #pragma unroll
            for (int ds = 0; ds < 2; ++ds) {
                f16x8 bf = *(const f16x8*)&kL[((ds * 4 + nt) * 64 + lane) * 8];
                s4 = __builtin_amdgcn_mfma_f32_16x16x32_f16(aq[ds], bf, s4, 0, 0, 0);
            }
            int k = c * 64 + nt * 16 + l15;
            float mk = maskL[k];
            int bi = k - qrow_base + 2047;
            #pragma unroll
            for (int r = 0; r < 4; ++r)
                lI[r] += __expf(s4[r] + biasL[bi - r] + mk);
        }
    }
    #pragma unroll
    for (int r = 0; r < 4; ++r) {
        float l = lI[r];
        l += __shfl_xor(l, 1, 64);
        l += __shfl_xor(l, 2, 64);
        l += __shfl_xor(l, 4, 64);
        l += __shfl_xor(l, 8, 64);
        lI[r] = 1.0f / l;
    }

    // ---- pass B: recompute scores, write weights, accumulate O = W*V ----
    float* wbase = wout + (size_t)bh * 2048 * 2048;
    f32x4 oacc[4];
    #pragma unroll
    for (int nt = 0; nt < 4; ++nt) oacc[nt] = (f32x4){0.f, 0.f, 0.f, 0.f};

    for (int c = 0; c < 32; ++c) {
        __syncthreads();
        #pragma unroll
        for (int s = 0; s < 2; ++s) {
            int f = wv + s * 4;
            {   // K frag
                int dstep = f >> 2, nt = f & 3;
                gload_lds16(&kB[(size_t)(c * 64 + nt * 16 + l15) * 64 + dstep * 32 + quad * 8],
                            &kL[(size_t)(s * 256 + wv * 64) * 8]);
            }
            {   // V frag
                int ks = f >> 2, nt = f & 3;
                gload_lds16(&vB[(size_t)(nt * 16 + l15) * 2048 + c * 64 + ks * 32 + quad * 8],
                            &vL[(size_t)(s * 256 + wv * 64) * 8]);
            }
        }
        __syncthreads();                 // drains vmcnt(0): kL/vL ready

        #pragma unroll
        for (int nt = 0; nt < 4; ++nt) {
            f32x4 s4 = (f32x4){0.f, 0.f, 0.f, 0.f};
            #pragma unroll
            for (int ds = 0; ds < 2; ++ds) {
                f16x8 bf = *(const f16x8*)&kL[((ds * 4 + nt) * 64 + lane) * 8];
                s4 = __builtin_amdgcn_mfma_f32_16x16x32_f16(aq[ds], bf, s4, 0, 0, 0);
            }
            int k = c * 64 + nt * 16 + l15;
            float mk = maskL[k];
            int bi = k - qrow_base + 2047;
            float* wp = wbase + (size_t)qrow_base * 2048 + k;
            #pragma unroll
            for (int r = 0; r < 4; ++r) {
                float w = __expf(s4[r] + biasL[bi - r] + mk) * lI[r];
                wp[(size_t)r * 2048] = w;
                wnat[wv * 1408 + (quad * 4 + r) * 88 + nt * 16 + l15] = (f16)w;
            }
        }
        // per-wave LDS RAW on wnat: compiler-inserted lgkmcnt; no barrier needed
        #pragma unroll
        for (int ks = 0; ks < 2; ++ks) {
            f16x8 wf = *(const f16x8*)&wnat[wv * 1408 + l15 * 88 + ks * 32 + quad * 8];
            #pragma unroll
            for (int nt = 0; nt < 4; ++nt) {
                f16x8 vf = *(const f16x8*)&vL[((ks * 4 + nt) * 64 + lane) * 8];
                oacc[nt] = __builtin_amdgcn_mfma_f32_16x16x32_f16(wf, vf, oacc[nt], 0, 0, 0);
            }
        }
    }

    #pragma unroll
    for (int nt = 0; nt < 4; ++nt) {
        int d = nt * 16 + l15;
        #pragma unroll
        for (int r = 0; r < 4; ++r) {
            int q = qrow_base + r;
            ctxh[((size_t)(b * 2048) + q) * 1024 + h * 64 + d] = (f16)oacc[nt][r];
        }
    }
}

// ---------- pos_bias ----------
// Fallback: recompute buckets (logf). Runs last over the scratch region.
__global__ __launch_bounds__(256)
void posbias_kernel(const float* __restrict__ rel_table, float* __restrict__ pb)
{
    size_t g = ((size_t)blockIdx.x * 256 + threadIdx.x) * 4;
    int k = (int)(g & 2047);
    int q = (int)((g >> 11) & 2047);
    int h = (int)(g >> 22);
    float4 r;
    float* rp = (float*)&r;
    #pragma unroll
    for (int j = 0; j < 4; ++j)
        rp[j] = rel_table[rel_bucket(k + j - q) * 16 + h];
    *(float4*)&pb[g] = r;
}

// Fast path: pure gather from a tbl copy living OUTSIDE pb (d_ws), no logf.
// pb[h][q][k..k+3] = tbl[h*4096 + (k-q+2047) .. +3]  (k..k+3 same row: k%4==0)
__global__ __launch_bounds__(256)
void posbias_tbl_kernel(const float* __restrict__ tblw, float* __restrict__ pb)
{
    size_t g = ((size_t)blockIdx.x * 256 + threadIdx.x) * 4;
    int k = (int)(g & 2047);
    int q = (int)((g >> 11) & 2047);
    int h = (int)(g >> 22);
    const float* tp = tblw + h * 4096 + (k - q + 2047);
    float4 r = { tp[0], tp[1], tp[2], tp[3] };
    *(float4*)&pb[g] = r;
}

extern "C" void kernel_launch(void* const* d_in, const int* in_sizes, int n_in,
                              void* d_out, int out_size, void* d_ws, size_t ws_size,
                              hipStream_t stream) {
    const float* x    = (const float*)d_in[0];
    const float* Wq   = (const float*)d_in[1];
    const float* bq   = (const float*)d_in[2];
    const float* Wk   = (const float*)d_in[3];
    const float* bk   = (const float*)d_in[4];
    const float* Wv   = (const float*)d_in[5];
    const float* bv   = (const float*)d_in[6];
    const float* Wo   = (const float*)d_in[7];
    const float* bo   = (const float*)d_in[8];
    const float* rt   = (const float*)d_in[9];
    const int*   mask = (const int*)d_in[10];

    float* out = (float*)d_out;
    float* wts = out + W_OFF;
    float* pb  = out + PB_OFF;

    // Scratch in the pos_bias region (67.1M floats); pos_bias written LAST.
    float* tbl  = pb;                         // 65,536 floats
    f16*   xh   = (f16*)(pb + 65536);         // 4,194,304 halfs
    f16*   wqt  = (f16*)(pb + 2162688);       // wq|wk|wv contiguous = [3072][1024]
    f16*   wkt  = (f16*)(pb + 2686976);
    f16*   wvt  = (f16*)(pb + 3211264);
    f16*   wot  = (f16*)(pb + 3735552);
    f16*   qh   = (f16*)(pb + 4259840);       // q|k|v contiguous, 4,194,304 halfs each
    f16*   kh   = (f16*)(pb + 6356992);
    f16*   vh   = (f16*)(pb + 8454144);
    f16*   vth  = (f16*)(pb + 10551296);
    f16*   ctxh = (f16*)(pb + 12648448);
    float* bqkv = pb + 14745600;              // 3072 floats

    const bool use_ws = ws_size >= 65536 * sizeof(float);
    float* tblw = (float*)d_ws;

    dim3 blk(256);
    conv_f16_kernel<<<dim3(4096), blk, 0, stream>>>(x, xh);
    transpose_w_kernel<<<dim3(16, 16), blk, 0, stream>>>(Wq, wqt);
    transpose_w_kernel<<<dim3(16, 16), blk, 0, stream>>>(Wk, wkt);
    transpose_w_kernel<<<dim3(16, 16), blk, 0, stream>>>(Wv, wvt);
    transpose_w_kernel<<<dim3(16, 16), blk, 0, stream>>>(Wo, wot);
    bias_tbl_kernel<<<dim3(256), blk, 0, stream>>>(rt, tbl);
    if (use_ws)
        bias_tbl_kernel<<<dim3(256), blk, 0, stream>>>(rt, tblw);
    concat_bias_kernel<<<dim3(12), blk, 0, stream>>>(bq, bk, bv, bqkv);

    // fused QKV projection: C[4096x3072], 768 blocks = 3/CU
    gemm_f16<<<dim3(24, 32), blk, 0, stream>>>(xh, wqt, bqkv, qh, 1);
    transpose_v_kernel<<<dim3(32, 32), blk, 0, stream>>>(vh, vth);

    attn_f16<<<dim3(32, 32), blk, 0, stream>>>(qh, kh, vth, tbl, mask, wts, ctxh);

    gemm_f16<<<dim3(8, 32), blk, 0, stream>>>(ctxh, wot, bo, out, 0);

    if (use_ws)
        posbias_tbl_kernel<<<dim3(65536), blk, 0, stream>>>(tblw, pb);
    else
        posbias_kernel<<<dim3(65536), blk, 0, stream>>>(rt, pb);
}